// Round 8
// baseline (96.391 us; speedup 1.0000x reference)
//
#include <hip/hip_runtime.h>

#define I_FEAT 256
#define O_FEAT 512
#define NSEG   8
#define KDIM   (I_FEAT * NSEG)   // 2048
#define KTOT   (2 * KDIM)        // 4096 (A-part || bias-part)
#define KC_N   (KTOT / 32)       // 128 K32-chunks

typedef _Float16 half8   __attribute__((ext_vector_type(8)));
typedef float    floatx4 __attribute__((ext_vector_type(4)));
typedef uint32_t uintx4  __attribute__((ext_vector_type(4)));

// ---------------- Kernel 1: weights -> B-fragment stream (XCD-aligned) ----------------
// bid%8 = n-tile = consumer XCD in kan_gemm (bid = nb + 8*mb) -> Bf lines stay
// dirty in the SAME XCD's L2 that will read them.
__global__ __launch_bounds__(256) void prep(
    const float* __restrict__ Aw,
    const float* __restrict__ Bw,
    uint4* __restrict__ Bf)
{
    __shared__ unsigned short T[64][72];   // [n][k] f16
    const int t   = threadIdx.x;
    const int bid = blockIdx.x;
    const int n0 = (bid & 7) * 64;
    const int k0 = (bid >> 3) * 64;
    const float* src = (k0 < KDIM) ? (Aw + (size_t)k0 * O_FEAT)
                                   : (Bw + (size_t)(k0 - KDIM) * O_FEAT);
    #pragma unroll
    for (int s = 0; s < 4; ++s) {
        int e  = s * 1024 + t * 4;
        int kl = e >> 6, nl = e & 63;
        const float4 v = *(const float4*)(src + (size_t)kl * O_FEAT + n0 + nl);
        T[nl + 0][kl] = __builtin_bit_cast(unsigned short, (_Float16)v.x);
        T[nl + 1][kl] = __builtin_bit_cast(unsigned short, (_Float16)v.y);
        T[nl + 2][kl] = __builtin_bit_cast(unsigned short, (_Float16)v.z);
        T[nl + 3][kl] = __builtin_bit_cast(unsigned short, (_Float16)v.w);
    }
    __syncthreads();

    const int lane = t & 63, lane16 = lane & 15, quad = lane >> 4;
    const int sub  = t >> 6;
    #pragma unroll
    for (int f = 0; f < 2; ++f) {
        const int combo = sub * 2 + f;       // 0..7
        const int n16g  = combo & 3;
        const int kch   = combo >> 2;
        const int nl = n16g * 16 + lane16;
        const int kl = kch * 32 + quad * 8;
        const uint4 val = *(const uint4*)&T[nl][kl];
        const int n16t = (n0 >> 4) + n16g;
        const int kc   = (k0 >> 5) + kch;
        Bf[((size_t)n16t * KC_N + kc) * 64 + lane] = val;
    }
}

// ---------------- Kernel 2: fused LN + meta-driven MFMA GEMM ----------------
// 512 thr = 8 waves: (ks = wave>>2) k-split-2 x (wm = (wave>>1)&1) m32 x
// (wn = wave&1) n32. Block tile 64m x 64n, K serial in 16 slabs of 8 kc.
// LN for the block's 64 rows computed in-kernel (meta in LDS; no Am stream,
// no cross-XCD dirty meta reads). B-frags via global_load_lds dbuf;
// 4 ds_read_b128 feed 8 MFMAs per kc (0.5 reads/MFMA).
static __device__ __forceinline__ half8 build_onehot(uint32_t u) {
    const uint32_t xb  = u & 0xFFFFu;
    const uint32_t seg = u >> 16;
    const uint64_t oh  = (uint64_t)xb << ((seg & 3u) << 4);
    const uint64_t lo  = (seg < 4u) ? oh : 0ull;
    const uint64_t hi  = (seg < 4u) ? 0ull : oh;
    uintx4 w;
    w[0] = (uint32_t)lo; w[1] = (uint32_t)(lo >> 32);
    w[2] = (uint32_t)hi; w[3] = (uint32_t)(hi >> 32);
    return __builtin_bit_cast(half8, w);
}

__global__ __launch_bounds__(512, 1) void kan_gemm(
    const float* __restrict__ x,
    const float* __restrict__ gamma,
    const float* __restrict__ beta,
    const uint4* __restrict__ Bf,
    float* __restrict__ out,
    int Bn)
{
    __shared__ uint4    bbuf[2][32][64];   // 64 KB  [buf][n16l*8+kcl][lane]
    __shared__ uint32_t M[64][258];        // 66 KB  [row][feat] meta

    const int t      = threadIdx.x;
    const int wave   = t >> 6, lane = t & 63;
    const int ks     = wave >> 2;          // k-split half
    const int wm     = (wave >> 1) & 1;    // m32 half
    const int wn     = wave & 1;           // n32 half
    const int lane16 = lane & 15, quad = lane >> 4;

    const int nb = blockIdx.x;             // XCD = (nb + 8*mb) % 8 = nb
    const int mb = blockIdx.y;

    // stage slab s into bbuf[b]: each of 8 waves stages 4 of 32 cells
    auto stage = [&](int s, int b) {
        const int kc0 = s * 8;
        #pragma unroll
        for (int j = 0; j < 4; ++j) {
            const int idx  = j * 8 + wave;
            const int n16l = idx >> 3, kcl = idx & 7;
            const uint4* g = Bf
                + ((size_t)((nb * 4 + n16l) * KC_N + kc0 + kcl)) * 64 + lane;
            __builtin_amdgcn_global_load_lds(
                (const __attribute__((address_space(1))) uint32_t*)g,
                (__attribute__((address_space(3))) uint32_t*)&bbuf[b][idx][lane],
                16, 0, 0);
        }
    };

    stage(0, 0);   // DMA flies under the LN phase

    // ---- LN phase: 8 threads per row, 64 rows ----
    {
        const int rl = t >> 3;            // row within tile
        const int c8 = t & 7;             // 32-feature stripe
        const int row = mb * 64 + rl;
        const bool ok = (row < Bn);
        const float* xr = x + (size_t)row * I_FEAT + c8 * 32;

        float4 v[8];
        #pragma unroll
        for (int j = 0; j < 8; ++j)
            v[j] = ok ? *(const float4*)(xr + j * 4) : make_float4(0.f, 0.f, 0.f, 0.f);

        float sum = 0.f, sq = 0.f;
        #pragma unroll
        for (int j = 0; j < 8; ++j) {
            sum += v[j].x + v[j].y + v[j].z + v[j].w;
            sq  += v[j].x * v[j].x + v[j].y * v[j].y
                 + v[j].z * v[j].z + v[j].w * v[j].w;
        }
        #pragma unroll
        for (int mask = 1; mask < 8; mask <<= 1) {   // 8-lane group reduce
            sum += __shfl_xor(sum, mask);
            sq  += __shfl_xor(sq,  mask);
        }
        const float mu  = sum * (1.0f / I_FEAT);
        const float var = sq * (1.0f / I_FEAT) - mu * mu;
        const float rs  = rsqrtf(var + 1e-5f);

        #pragma unroll
        for (int j = 0; j < 8; ++j) {
            const int cb = c8 * 32 + j * 4;
            const float4 g4 = *(const float4*)(gamma + cb);
            const float4 b4 = *(const float4*)(beta  + cb);
            const float vv[4] = { v[j].x, v[j].y, v[j].z, v[j].w };
            const float gg[4] = { g4.x, g4.y, g4.z, g4.w };
            const float bb[4] = { b4.x, b4.y, b4.z, b4.w };
            #pragma unroll
            for (int e = 0; e < 4; ++e) {
                float xn = (vv[e] - mu) * rs * gg[e] + bb[e];
                float fi = (xn + 1.0f) * 4.0f;   // (xn-GRID_MIN)/STEP, exact fp32
                int seg = (int)fi;                // trunc == jnp astype(int32)
                seg = seg < 0 ? 0 : (seg > NSEG - 1 ? NSEG - 1 : seg);
                _Float16 hx = (_Float16)xn;
                M[rl][cb + e] = ((uint32_t)seg << 16)
                              | (uint32_t)__builtin_bit_cast(unsigned short, hx);
            }
        }
    }
    __syncthreads();   // M ready AND slab-0 DMA drained (vmcnt at barrier)

    floatx4 acc[2][2] = {};
    const int ml0 = wm * 32 + lane16;      // meta rows for sm=0 (sm=1: +16)

    for (int s = 0; s < 16; ++s) {
        const int b = s & 1;
        if (s < 15) stage(s + 1, b ^ 1);
        const uint32_t isBias = (s >= 8);  // kc>=64 <=> bias part

        #pragma unroll
        for (int c = 0; c < 4; ++c) {
            const int kcl = ks * 4 + c;          // kc within slab
            const int kc  = s * 8 + kcl;
            const int i   = (kc * 4 + quad) & 255;

            const half8 b0 = __builtin_bit_cast(half8, bbuf[b][(wn * 2 + 0) * 8 + kcl][lane]);
            const half8 b1 = __builtin_bit_cast(half8, bbuf[b][(wn * 2 + 1) * 8 + kcl][lane]);

            uint32_t u0 = M[ml0][i];
            uint32_t u1 = M[ml0 + 16][i];
            if (isBias) {
                u0 = (u0 & 0xFFFF0000u) | 0x3C00u;   // coefficient f16(1.0)
                u1 = (u1 & 0xFFFF0000u) | 0x3C00u;
            }
            const half8 a0 = build_onehot(u0);
            const half8 a1 = build_onehot(u1);
            acc[0][0] = __builtin_amdgcn_mfma_f32_16x16x32_f16(a0, b0, acc[0][0], 0, 0, 0);
            acc[0][1] = __builtin_amdgcn_mfma_f32_16x16x32_f16(a0, b1, acc[0][1], 0, 0, 0);
            acc[1][0] = __builtin_amdgcn_mfma_f32_16x16x32_f16(a1, b0, acc[1][0], 0, 0, 0);
            acc[1][1] = __builtin_amdgcn_mfma_f32_16x16x32_f16(a1, b1, acc[1][1], 0, 0, 0);
        }
        __syncthreads();   // bbuf[b] reads done; next slab DMA drained
    }

    // ---- k-split reduction (overlay on bbuf) + store ----
    float* red = (float*)bbuf;     // 4 slots x 16 x 64 floats = 16 KB
    const int slot = wm * 2 + wn;
    if (ks == 1) {
        #pragma unroll
        for (int sm = 0; sm < 2; ++sm)
            #pragma unroll
            for (int sn = 0; sn < 2; ++sn)
                #pragma unroll
                for (int r = 0; r < 4; ++r)
                    red[(slot * 16 + (sm * 2 + sn) * 4 + r) * 64 + lane] = acc[sm][sn][r];
    }
    __syncthreads();
    if (ks == 0) {
        #pragma unroll
        for (int sm = 0; sm < 2; ++sm) {
            const int grow0 = mb * 64 + wm * 32 + sm * 16 + quad * 4;
            #pragma unroll
            for (int sn = 0; sn < 2; ++sn) {
                const int gcol = nb * 64 + wn * 32 + sn * 16 + lane16;
                #pragma unroll
                for (int r = 0; r < 4; ++r) {
                    const int grow = grow0 + r;
                    if (grow < Bn) {
                        const float v = acc[sm][sn][r]
                            + red[(slot * 16 + (sm * 2 + sn) * 4 + r) * 64 + lane];
                        out[(size_t)grow * O_FEAT + gcol] = v;
                    }
                }
            }
        }
    }
}

extern "C" void kernel_launch(void* const* d_in, const int* in_sizes, int n_in,
                              void* d_out, int out_size, void* d_ws, size_t ws_size,
                              hipStream_t stream) {
    const float* x   = (const float*)d_in[0];
    const float* Aw  = (const float*)d_in[1];
    const float* Bw  = (const float*)d_in[2];
    const float* gam = (const float*)d_in[3];
    const float* bet = (const float*)d_in[4];
    float* out       = (float*)d_out;

    const int Bn      = in_sizes[0] / I_FEAT;
    const int mb64Tot = (Bn + 63) / 64;
    const int pbTot   = (O_FEAT / 64) * (KTOT / 64);   // 512

    uint4* Bf = (uint4*)d_ws;   // 4 MB

    hipLaunchKernelGGL(prep, dim3(pbTot), dim3(256), 0, stream, Aw, Bw, Bf);
    hipLaunchKernelGGL(kan_gemm, dim3(O_FEAT / 64, mb64Tot), dim3(512), 0, stream,
                       x, gam, bet, Bf, out, Bn);
}

// Round 10
// 90.557 us; speedup vs baseline: 1.0644x; 1.0644x over previous
//
#include <hip/hip_runtime.h>

#define I_FEAT 256
#define O_FEAT 512
#define NSEG   8
#define KDIM   (I_FEAT * NSEG)   // 2048
#define KTOT   (2 * KDIM)        // 4096 (A-part || bias-part)
#define KC_N   (KTOT / 32)       // 128 K32-chunks

typedef _Float16 half8   __attribute__((ext_vector_type(8)));
typedef float    floatx4 __attribute__((ext_vector_type(4)));
typedef uint32_t uintx4  __attribute__((ext_vector_type(4)));
typedef uint32_t uintx2  __attribute__((ext_vector_type(2)));

// ---------------- Kernel 1: prep (pack_bfrag ∪ fused LN->Am), bid-split ----------------
// All d_ws outputs use NON-TEMPORAL stores: lines land clean in L3 instead of
// dirty in the writer-XCD's L2 -> readers on other XCDs skip the dirty-snoop
// round-trip (the R5-R8 structure-insensitive ~30us GEMM stall suspect).
__global__ __launch_bounds__(256) void prep(
    const float* __restrict__ x,
    const float* __restrict__ Aw,
    const float* __restrict__ Bw,
    const float* __restrict__ gamma,
    const float* __restrict__ beta,
    uint4* __restrict__ Bf,
    uint2* __restrict__ Am,
    int Bn, int pbTot)
{
    __shared__ uint32_t smem[16 * 260];   // 16640 B, reused by both paths
    const int t   = threadIdx.x;
    const int bid = blockIdx.x;

    if (bid < pbTot) {
        // ---- weight pack path: one 64n x 64k tile -> B-fragment stream ----
        unsigned short (*T)[72] = (unsigned short(*)[72])smem;  // [n][k] f16
        const int n0 = (bid & 7) * 64;
        const int k0 = (bid >> 3) * 64;
        const float* src = (k0 < KDIM) ? (Aw + (size_t)k0 * O_FEAT)
                                       : (Bw + (size_t)(k0 - KDIM) * O_FEAT);
        #pragma unroll
        for (int s = 0; s < 4; ++s) {
            int e  = s * 1024 + t * 4;
            int kl = e >> 6, nl = e & 63;
            const float4 v = *(const float4*)(src + (size_t)kl * O_FEAT + n0 + nl);
            T[nl + 0][kl] = __builtin_bit_cast(unsigned short, (_Float16)v.x);
            T[nl + 1][kl] = __builtin_bit_cast(unsigned short, (_Float16)v.y);
            T[nl + 2][kl] = __builtin_bit_cast(unsigned short, (_Float16)v.z);
            T[nl + 3][kl] = __builtin_bit_cast(unsigned short, (_Float16)v.w);
        }
        __syncthreads();

        const int lane = t & 63, lane16 = lane & 15, quad = lane >> 4;
        const int sub  = t >> 6;
        #pragma unroll
        for (int f = 0; f < 2; ++f) {
            const int combo = sub * 2 + f;       // 0..7
            const int n16g  = combo & 3;
            const int kch   = combo >> 2;
            const int nl = n16g * 16 + lane16;
            const int kl = kch * 32 + quad * 8;
            const uintx4 val = *(const uintx4*)&T[nl][kl];
            const int n16t = (n0 >> 4) + n16g;
            const int kc   = (k0 >> 5) + kch;
            __builtin_nontemporal_store(val,
                (uintx4*)&Bf[((size_t)n16t * KC_N + kc) * 64 + lane]);
        }
    } else {
        // ---- LN -> Am path: one mt16 (16 rows), 16 threads per row ----
        uint32_t (*M)[260] = (uint32_t(*)[260])smem;   // [row][feat]
        const int mt16 = bid - pbTot;
        const int rr   = t >> 4;
        const int c16  = t & 15;
        const int row  = mt16 * 16 + rr;
        const bool ok  = (row < Bn);

        float4 v[4];
        const float* xr = x + (size_t)row * I_FEAT + c16 * 16;
        #pragma unroll
        for (int j = 0; j < 4; ++j)
            v[j] = ok ? *(const float4*)(xr + j * 4) : make_float4(0.f, 0.f, 0.f, 0.f);

        float sum = 0.f, sq = 0.f;
        #pragma unroll
        for (int j = 0; j < 4; ++j) {
            sum += v[j].x + v[j].y + v[j].z + v[j].w;
            sq  += v[j].x * v[j].x + v[j].y * v[j].y
                 + v[j].z * v[j].z + v[j].w * v[j].w;
        }
        #pragma unroll
        for (int mask = 1; mask < 16; mask <<= 1) {
            sum += __shfl_xor(sum, mask);
            sq  += __shfl_xor(sq,  mask);
        }
        const float mu  = sum * (1.0f / I_FEAT);
        const float var = sq * (1.0f / I_FEAT) - mu * mu;
        const float rs  = rsqrtf(var + 1e-5f);

        #pragma unroll
        for (int j = 0; j < 4; ++j) {
            const float4 g4 = *(const float4*)(gamma + c16 * 16 + j * 4);
            const float4 b4 = *(const float4*)(beta  + c16 * 16 + j * 4);
            const float vv[4] = { v[j].x, v[j].y, v[j].z, v[j].w };
            const float gg[4] = { g4.x, g4.y, g4.z, g4.w };
            const float bb[4] = { b4.x, b4.y, b4.z, b4.w };
            #pragma unroll
            for (int e = 0; e < 4; ++e) {
                const int c = c16 * 16 + j * 4 + e;
                float xn = (vv[e] - mu) * rs * gg[e] + bb[e];
                float fi = (xn + 1.0f) * 4.0f;   // (xn - GRID_MIN)/STEP, exact fp32
                int seg = (int)fi;                // trunc == jnp astype(int32)
                seg = seg < 0 ? 0 : (seg > NSEG - 1 ? NSEG - 1 : seg);
                _Float16 hx = (_Float16)xn;
                M[rr][c] = ((uint32_t)seg << 16)
                         | (uint32_t)__builtin_bit_cast(unsigned short, hx);
            }
        }
        __syncthreads();

        // emit Am: word(m,w): w<256 -> meta; w>=256 -> (seg<<16 | f16(1.0))
        const int lane = t & 63, g = t >> 6;
        const int m_local = lane & 15, quad = lane >> 4;
        uint2* dst = Am + (size_t)mt16 * 64 * 64 + lane;
        #pragma unroll
        for (int kk = 0; kk < 16; ++kk) {
            const int kcp = g * 16 + kk;
            const int w0  = kcp * 8 + quad;
            const int w1  = w0 + 4;
            const uint32_t u0 = M[m_local][w0 & 255];
            const uint32_t u1 = M[m_local][w1 & 255];
            const uint32_t a  = (w0 >> 8) ? ((u0 & 0xFFFF0000u) | 0x3C00u) : u0;
            const uint32_t b  = (w1 >> 8) ? ((u1 & 0xFFFF0000u) | 0x3C00u) : u1;
            uintx2 pv; pv[0] = a; pv[1] = b;
            __builtin_nontemporal_store(pv, (uintx2*)&dst[(size_t)kcp * 64]);
        }
    }
}

// ---------------- Kernel 2: streaming MFMA GEMM, 64m x 32n, k-split-4 ----------------
static __device__ __forceinline__ half8 build_onehot(uint32_t u) {
    const uint32_t xb  = u & 0xFFFFu;
    const uint32_t seg = u >> 16;
    const uint64_t oh  = (uint64_t)xb << ((seg & 3u) << 4);
    const uint64_t lo  = (seg < 4u) ? oh : 0ull;
    const uint64_t hi  = (seg < 4u) ? 0ull : oh;
    uintx4 w;
    w[0] = (uint32_t)lo; w[1] = (uint32_t)(lo >> 32);
    w[2] = (uint32_t)hi; w[3] = (uint32_t)(hi >> 32);
    return __builtin_bit_cast(half8, w);
}

__global__ __launch_bounds__(256, 2) void kan_gemm(
    const uint2* __restrict__ Am,
    const uint4* __restrict__ Bf,
    float* __restrict__ out,
    int Bn, int rt64Tot)
{
    __shared__ floatx4 s_red[4][8][64];   // 32 KB

    const int t      = threadIdx.x;
    const int wave   = t >> 6, lane = t & 63;
    const int lane16 = lane & 15, quad = lane >> 4;
    const int bid    = blockIdx.x;

    int ot, rt;
    if (rt64Tot == 32) {
        // XCD-aware decode (XCD = bid%8): per XCD 4 ot (1MB Bf) x 16 rt (2MB Am)
        const int xc = bid & 7, j = bid >> 3;
        ot = ((j >> 4) << 2) | (xc & 3);
        rt = (j & 15) | ((xc >> 2) << 4);
    } else {
        ot = bid & 15;
        rt = bid >> 4;
    }

    const uint2* pa = Am + (size_t)(rt * 4) * 64 * 64 + lane;     // 4 mt16 streams
    const uint4* pb = Bf + (size_t)(ot * 2) * KC_N * 64 + lane;   // 2 n16t streams

    floatx4 acc[4][2] = {};
    const int kcp0 = wave * 16;   // 4-way kc split

    #pragma unroll 4
    for (int p = 0; p < 16; ++p) {
        const int kcp = kcp0 + p;
        const uint2 u0 = pa[(size_t)kcp * 64];
        const uint2 u1 = pa[(size_t)(4096  + kcp * 64)];
        const uint2 u2 = pa[(size_t)(8192  + kcp * 64)];
        const uint2 u3 = pa[(size_t)(12288 + kcp * 64)];
        const uint4 b00 = pb[(size_t)(2 * kcp + 0) * 64];
        const uint4 b01 = pb[(size_t)(2 * kcp + 1) * 64];
        const uint4 b10 = pb[(size_t)(8192 + (2 * kcp + 0) * 64)];
        const uint4 b11 = pb[(size_t)(8192 + (2 * kcp + 1) * 64)];
        {   // kc = 2*kcp
            const half8 n0 = __builtin_bit_cast(half8, b00);
            const half8 n1 = __builtin_bit_cast(half8, b10);
            half8 a;
            a = build_onehot(u0.x);
            acc[0][0] = __builtin_amdgcn_mfma_f32_16x16x32_f16(a, n0, acc[0][0], 0, 0, 0);
            acc[0][1] = __builtin_amdgcn_mfma_f32_16x16x32_f16(a, n1, acc[0][1], 0, 0, 0);
            a = build_onehot(u1.x);
            acc[1][0] = __builtin_amdgcn_mfma_f32_16x16x32_f16(a, n0, acc[1][0], 0, 0, 0);
            acc[1][1] = __builtin_amdgcn_mfma_f32_16x16x32_f16(a, n1, acc[1][1], 0, 0, 0);
            a = build_onehot(u2.x);
            acc[2][0] = __builtin_amdgcn_mfma_f32_16x16x32_f16(a, n0, acc[2][0], 0, 0, 0);
            acc[2][1] = __builtin_amdgcn_mfma_f32_16x16x32_f16(a, n1, acc[2][1], 0, 0, 0);
            a = build_onehot(u3.x);
            acc[3][0] = __builtin_amdgcn_mfma_f32_16x16x32_f16(a, n0, acc[3][0], 0, 0, 0);
            acc[3][1] = __builtin_amdgcn_mfma_f32_16x16x32_f16(a, n1, acc[3][1], 0, 0, 0);
        }
        {   // kc = 2*kcp + 1
            const half8 n0 = __builtin_bit_cast(half8, b01);
            const half8 n1 = __builtin_bit_cast(half8, b11);
            half8 a;
            a = build_onehot(u0.y);
            acc[0][0] = __builtin_amdgcn_mfma_f32_16x16x32_f16(a, n0, acc[0][0], 0, 0, 0);
            acc[0][1] = __builtin_amdgcn_mfma_f32_16x16x32_f16(a, n1, acc[0][1], 0, 0, 0);
            a = build_onehot(u1.y);
            acc[1][0] = __builtin_amdgcn_mfma_f32_16x16x32_f16(a, n0, acc[1][0], 0, 0, 0);
            acc[1][1] = __builtin_amdgcn_mfma_f32_16x16x32_f16(a, n1, acc[1][1], 0, 0, 0);
            a = build_onehot(u2.y);
            acc[2][0] = __builtin_amdgcn_mfma_f32_16x16x32_f16(a, n0, acc[2][0], 0, 0, 0);
            acc[2][1] = __builtin_amdgcn_mfma_f32_16x16x32_f16(a, n1, acc[2][1], 0, 0, 0);
            a = build_onehot(u3.y);
            acc[3][0] = __builtin_amdgcn_mfma_f32_16x16x32_f16(a, n0, acc[3][0], 0, 0, 0);
            acc[3][1] = __builtin_amdgcn_mfma_f32_16x16x32_f16(a, n1, acc[3][1], 0, 0, 0);
        }
    }

    // cross-wave kc reduction: every wave dumps all 8 tiles, then sums 2 tiles.
    #pragma unroll
    for (int mi = 0; mi < 4; ++mi)
        #pragma unroll
        for (int ni = 0; ni < 2; ++ni)
            s_red[wave][mi * 2 + ni][lane] = acc[mi][ni];
    __syncthreads();

    #pragma unroll
    for (int q = 0; q < 2; ++q) {
        const int tt = wave * 2 + q;
        const int mi = tt >> 1, ni = tt & 1;
        floatx4 vsum = s_red[0][tt][lane];
        vsum += s_red[1][tt][lane];
        vsum += s_red[2][tt][lane];
        vsum += s_red[3][tt][lane];
        const int gcol = ot * 32 + ni * 16 + lane16;
        const int gr0  = rt * 64 + mi * 16 + quad * 4;
        #pragma unroll
        for (int r = 0; r < 4; ++r) {
            const int grow = gr0 + r;
            if (grow < Bn)
                out[(size_t)grow * O_FEAT + gcol] = vsum[r];
        }
    }
}

extern "C" void kernel_launch(void* const* d_in, const int* in_sizes, int n_in,
                              void* d_out, int out_size, void* d_ws, size_t ws_size,
                              hipStream_t stream) {
    const float* x   = (const float*)d_in[0];
    const float* Aw  = (const float*)d_in[1];
    const float* Bw  = (const float*)d_in[2];
    const float* gam = (const float*)d_in[3];
    const float* bet = (const float*)d_in[4];
    float* out       = (float*)d_out;

    const int Bn      = in_sizes[0] / I_FEAT;
    const int mt16Tot = (Bn + 15) / 16;
    const int rt64Tot = (Bn + 63) / 64;
    const int pbTot   = (O_FEAT / 64) * (KTOT / 64);   // 512

    // ws: Bf 4MB | Am (mt16Tot*64*64*8B)
    uint4* Bf = (uint4*)d_ws;
    uint2* Am = (uint2*)(Bf + (size_t)(O_FEAT / 16) * KC_N * 64);

    hipLaunchKernelGGL(prep, dim3(pbTot + mt16Tot), dim3(256), 0, stream,
                       x, Aw, Bw, gam, bet, Bf, Am, Bn, pbTot);
    hipLaunchKernelGGL(kan_gemm, dim3(16 * rt64Tot), dim3(256), 0, stream,
                       Am, Bf, out, Bn, rt64Tot);
}